// Round 12
// baseline (118.878 us; speedup 1.0000x reference)
//
#include <hip/hip_runtime.h>

#define BATCH 4096
#define DIM   128
#define TILE  256
#define NT    16   // 4096 / 256 tiles per dimension
// TEMP = 0.25 -> 1/T = 4; 4*log2(e):
#define EXP_SCALE 5.770780163555854f

typedef __bf16 bf16_t;
typedef __bf16 bf16x8 __attribute__((ext_vector_type(8)));
typedef float  f32x4  __attribute__((ext_vector_type(4)));

// ---------------------------------------------------------------------------
// Kernel A: per row k, normalize emb_i[k] and emb_j[k] (fp32 math), write
// bf16 z_i, z_j to workspace, pos[k] = cos-sim in fp32. One wave per row.
// Blocks 0..7 zero exactly the rowDenom/colDenom region (32 KB), race-free.
// (Byte-identical to the proven R8 kernel.)
// ---------------------------------------------------------------------------
__global__ __launch_bounds__(256) void normalize_kernel(
    const float* __restrict__ emb_i, const float* __restrict__ emb_j,
    bf16_t* __restrict__ zi, bf16_t* __restrict__ zj, float* __restrict__ pos,
    float* __restrict__ denoms /* rowDenom(4096) ++ colDenom(4096) */)
{
    if (blockIdx.x < 8) {
        int idx = (blockIdx.x * 256 + threadIdx.x) * 4;
        *(float4*)&denoms[idx] = make_float4(0.f, 0.f, 0.f, 0.f);
    }

    int wave = threadIdx.x >> 6;
    int lane = threadIdx.x & 63;
    int k = blockIdx.x * 4 + wave;

    const float2* ei = (const float2*)(emb_i + (size_t)k * DIM);
    const float2* ej = (const float2*)(emb_j + (size_t)k * DIM);
    float2 a = ei[lane];
    float2 b = ej[lane];

    float sii = a.x * a.x + a.y * a.y;
    float sjj = b.x * b.x + b.y * b.y;
    float sij = a.x * b.x + a.y * b.y;
#pragma unroll
    for (int m = 1; m < 64; m <<= 1) {
        sii += __shfl_xor(sii, m);
        sjj += __shfl_xor(sjj, m);
        sij += __shfl_xor(sij, m);
    }
    float inv_i = 1.0f / fmaxf(sqrtf(sii), 1e-12f);
    float inv_j = 1.0f / fmaxf(sqrtf(sjj), 1e-12f);

    struct bf16_2 { bf16_t x, y; };
    bf16_2 pi, pj;
    pi.x = (bf16_t)(a.x * inv_i);  pi.y = (bf16_t)(a.y * inv_i);
    pj.x = (bf16_t)(b.x * inv_j);  pj.y = (bf16_t)(b.y * inv_j);
    ((bf16_2*)(zi + (size_t)k * DIM))[lane] = pi;
    ((bf16_2*)(zj + (size_t)k * DIM))[lane] = pj;

    if (lane == 0) pos[k] = sij * inv_i * inv_j;
}

// ---------------------------------------------------------------------------
// Kernel B: 256x256 tile per block (grid 16x16 = 256 blocks = 1/CU).
// WHY (R11 probe): the 128^2 kernel measured 15.5us and is L2-staging
// bound -- 1024 blocks x 256KB = 256 MB of L2 traffic (7.4us at the
// 34.5TB/s ceiling) + 2x the LDS-read per CU. Staging scales as 1/TILE:
// 256^2 -> 256 blocks x 128KB = 32 MB (~1us). This is R0's direction
// WITHOUT R0's mistakes: no __launch_bounds__ min-waves VGPR cap (R0's
// (512,2) capped at 128 VGPR -> spill), no fused normalize, proven
// atomic output path (R10: partials +18us).
// 512 threads = 8 waves in a 2x4 grid; each wave owns 128x64:
// acc[8][4] f32x4 = 128 VGPR (+~60 frags/temps -> ~200, 2 waves/SIMD).
// LDS: 2 x 256x136 bf16 = 139KB (<160) + 6KB reduce buffers.
// Padded-136 rows: same free 2-way bank pattern as baseline.
// Epilogue: row sums cross-wave (4 wc-waves) via LDS -> 1 atomic/row;
// col sums cross-wave (2 wr-waves) via LDS -> 1 atomic/col.
// ---------------------------------------------------------------------------
__global__ void gemm_exp_kernel(
    const bf16_t* __restrict__ zi, const bf16_t* __restrict__ zj,
    float* __restrict__ rowDenom, float* __restrict__ colDenom)
{
    __shared__ __align__(16) bf16_t zi_s[TILE][136];
    __shared__ __align__(16) bf16_t zj_s[TILE][136];
    __shared__ float rowRed[4][TILE];
    __shared__ float colRed[2][TILE];

    const int tid = threadIdx.x;
    const int ti = blockIdx.x, tj = blockIdx.y;

    // Stage 256x128 bf16 of each matrix: 4096 16B-chunks / matrix, 8 iters.
#pragma unroll
    for (int it = 0; it < 8; ++it) {
        int c = it * 512 + tid;
        int row = c >> 4;          // 16 chunks per row
        int col = (c & 15) << 3;   // 8 bf16 per chunk
        *(uint4*)&zi_s[row][col] =
            *(const uint4*)(zi + ((size_t)(ti * TILE + row)) * DIM + col);
        *(uint4*)&zj_s[row][col] =
            *(const uint4*)(zj + ((size_t)(tj * TILE + row)) * DIM + col);
    }
    __syncthreads();

    const int wave = tid >> 6;
    const int lane = tid & 63;
    const int l15  = lane & 15;
    const int quad = lane >> 4;
    const int wr   = wave >> 2;   // 0..1 : row half    (128 rows)
    const int wc   = wave & 3;    // 0..3 : col quarter (64 cols)

    const f32x4 vzero = {0.f, 0.f, 0.f, 0.f};
    f32x4 acc[8][4];
#pragma unroll
    for (int mr = 0; mr < 8; ++mr)
#pragma unroll
        for (int nc = 0; nc < 4; ++nc) acc[mr][nc] = vzero;

#pragma unroll
    for (int ks = 0; ks < 4; ++ks) {
        int k0 = ks * 32 + quad * 8;
        bf16x8 afrag[8], bfrag[4];
#pragma unroll
        for (int mr = 0; mr < 8; ++mr)
            afrag[mr] = *(const bf16x8*)&zi_s[wr * 128 + mr * 16 + l15][k0];
#pragma unroll
        for (int nc = 0; nc < 4; ++nc)
            bfrag[nc] = *(const bf16x8*)&zj_s[wc * 64 + nc * 16 + l15][k0];
#pragma unroll
        for (int mr = 0; mr < 8; ++mr)
#pragma unroll
            for (int nc = 0; nc < 4; ++nc)
                acc[mr][nc] = __builtin_amdgcn_mfma_f32_16x16x32_bf16(
                    afrag[mr], bfrag[nc], acc[mr][nc], 0, 0, 0);
    }

    // Epilogue: exp and partial sums.
    // C/D layout: col = l15, row = quad*4 + r (within each 16x16 frag).
    float rowPart[8][4];
    float colPart[4] = {0.f, 0.f, 0.f, 0.f};
#pragma unroll
    for (int mr = 0; mr < 8; ++mr)
#pragma unroll
        for (int r = 0; r < 4; ++r) rowPart[mr][r] = 0.f;

#pragma unroll
    for (int mr = 0; mr < 8; ++mr)
#pragma unroll
        for (int nc = 0; nc < 4; ++nc)
#pragma unroll
            for (int r = 0; r < 4; ++r) {
                float e = exp2f(acc[mr][nc][r] * EXP_SCALE);
                rowPart[mr][r] += e;   // row = wr*128 + mr*16 + quad*4 + r
                colPart[nc]    += e;   // col = wc*64  + nc*16 + l15
            }

    // Row sums: 16-lane shfl completes this wave's 64 cols; cross-wave
    // (4 wc-waves) via LDS.
#pragma unroll
    for (int mr = 0; mr < 8; ++mr)
#pragma unroll
        for (int r = 0; r < 4; ++r) {
            float v = rowPart[mr][r];
            v += __shfl_xor(v, 1);
            v += __shfl_xor(v, 2);
            v += __shfl_xor(v, 4);
            v += __shfl_xor(v, 8);
            if (l15 == 0)
                rowRed[wc][wr * 128 + mr * 16 + quad * 4 + r] = v;
        }

    // Col sums: quad shfl-reduce completes this wave's 128 rows;
    // cross-wave (2 wr-waves) via LDS.
#pragma unroll
    for (int nc = 0; nc < 4; ++nc) {
        float v = colPart[nc];
        v += __shfl_xor(v, 16);
        v += __shfl_xor(v, 32);
        if (quad == 0) colRed[wr][wc * 64 + nc * 16 + l15] = v;
    }
    __syncthreads();

    if (tid < TILE) {
        float rs = rowRed[0][tid] + rowRed[1][tid] + rowRed[2][tid] + rowRed[3][tid];
        atomicAdd(&rowDenom[ti * TILE + tid], rs);
        float cs = colRed[0][tid] + colRed[1][tid];
        atomicAdd(&colDenom[tj * TILE + tid], cs);
    }
}

// ---------------------------------------------------------------------------
// Kernel C: 1 block x 1024 threads; 3 independent float4 loads per thread,
// 8 logf, wave shfl-reduce, 16-way LDS reduce (R8 version).
// ---------------------------------------------------------------------------
__global__ __launch_bounds__(1024) void finalize_kernel(
    const float* __restrict__ denoms, const float* __restrict__ pos,
    float* __restrict__ out)
{
    const float4* rowD4 = (const float4*)denoms;            // 1024 float4
    const float4* colD4 = (const float4*)(denoms + BATCH);  // 1024 float4
    const float4* pos4  = (const float4*)pos;               // 1024 float4

    const int tid  = threadIdx.x;
    const int lane = tid & 63;
    const int wv   = tid >> 6;

    float4 rd = rowD4[tid];
    float4 cd = colD4[tid];
    float4 p  = pos4[tid];

    float acc = logf(rd.x) + logf(rd.y) + logf(rd.z) + logf(rd.w)
              + logf(cd.x) + logf(cd.y) + logf(cd.z) + logf(cd.w)
              - 8.0f * (p.x + p.y + p.z + p.w);

#pragma unroll
    for (int m = 1; m < 64; m <<= 1) acc += __shfl_xor(acc, m);

    __shared__ float red[16];
    if (lane == 0) red[wv] = acc;
    __syncthreads();
    if (wv == 0) {
        float v = (lane < 16) ? red[lane] : 0.0f;
#pragma unroll
        for (int m = 1; m < 64; m <<= 1) v += __shfl_xor(v, m);
        if (lane == 0) out[0] = v * (1.0f / (2.0f * BATCH));
    }
}

extern "C" void kernel_launch(void* const* d_in, const int* in_sizes, int n_in,
                              void* d_out, int out_size, void* d_ws, size_t ws_size,
                              hipStream_t stream) {
    const float* emb_i = (const float*)d_in[0];
    const float* emb_j = (const float*)d_in[1];
    float* out = (float*)d_out;

    char* ws = (char*)d_ws;
    bf16_t* zi     = (bf16_t*)(ws);                 // 1 MB
    bf16_t* zj     = (bf16_t*)(ws + (1u << 20));    // 1 MB
    float*  denoms = (float*)(ws + (2u << 20));     // 32 KB (row ++ col)
    float*  pos    = denoms + 2 * BATCH;            // 16 KB

    normalize_kernel<<<BATCH / 4, 256, 0, stream>>>(emb_i, emb_j, zi, zj, pos, denoms);
    gemm_exp_kernel<<<dim3(NT, NT), 512, 0, stream>>>(zi, zj, denoms, denoms + BATCH);
    finalize_kernel<<<1, 1024, 0, stream>>>(denoms, pos, out);
}

// Round 13
// 75.152 us; speedup vs baseline: 1.5818x; 1.5818x over previous
//
#include <hip/hip_runtime.h>

#define BATCH 4096
#define DIM   128
#define TILE  256
#define NT    16   // 4096 / 256 tiles per dimension
// TEMP = 0.25 -> 1/T = 4; 4*log2(e):
#define EXP_SCALE 5.770780163555854f

typedef __bf16 bf16_t;
typedef __bf16 bf16x8 __attribute__((ext_vector_type(8)));
typedef float  f32x4  __attribute__((ext_vector_type(4)));

// ---------------------------------------------------------------------------
// Kernel A: per row k, normalize emb_i[k] and emb_j[k] (fp32 math), write
// bf16 z_i, z_j to workspace, pos[k] = cos-sim in fp32. One wave per row.
// Blocks 0..7 zero exactly the rowDenom/colDenom region (32 KB), race-free.
// (Byte-identical to the proven R8 kernel.)
// ---------------------------------------------------------------------------
__global__ __launch_bounds__(256) void normalize_kernel(
    const float* __restrict__ emb_i, const float* __restrict__ emb_j,
    bf16_t* __restrict__ zi, bf16_t* __restrict__ zj, float* __restrict__ pos,
    float* __restrict__ denoms /* rowDenom(4096) ++ colDenom(4096) */)
{
    if (blockIdx.x < 8) {
        int idx = (blockIdx.x * 256 + threadIdx.x) * 4;
        *(float4*)&denoms[idx] = make_float4(0.f, 0.f, 0.f, 0.f);
    }

    int wave = threadIdx.x >> 6;
    int lane = threadIdx.x & 63;
    int k = blockIdx.x * 4 + wave;

    const float2* ei = (const float2*)(emb_i + (size_t)k * DIM);
    const float2* ej = (const float2*)(emb_j + (size_t)k * DIM);
    float2 a = ei[lane];
    float2 b = ej[lane];

    float sii = a.x * a.x + a.y * a.y;
    float sjj = b.x * b.x + b.y * b.y;
    float sij = a.x * b.x + a.y * b.y;
#pragma unroll
    for (int m = 1; m < 64; m <<= 1) {
        sii += __shfl_xor(sii, m);
        sjj += __shfl_xor(sjj, m);
        sij += __shfl_xor(sij, m);
    }
    float inv_i = 1.0f / fmaxf(sqrtf(sii), 1e-12f);
    float inv_j = 1.0f / fmaxf(sqrtf(sjj), 1e-12f);

    struct bf16_2 { bf16_t x, y; };
    bf16_2 pi, pj;
    pi.x = (bf16_t)(a.x * inv_i);  pi.y = (bf16_t)(a.y * inv_i);
    pj.x = (bf16_t)(b.x * inv_j);  pj.y = (bf16_t)(b.y * inv_j);
    ((bf16_2*)(zi + (size_t)k * DIM))[lane] = pi;
    ((bf16_2*)(zj + (size_t)k * DIM))[lane] = pj;

    if (lane == 0) pos[k] = sij * inv_i * inv_j;
}

// ---------------------------------------------------------------------------
// Kernel B: 256x256 tile per block (grid 16x16 = 256 blocks = 1/CU).
// R11 probe: 128^2 K2 = 15.5us, L2-staging bound (1024 x 256KB = 256 MB
// of L2 traffic); staging scales 1/TILE -> 256^2 = 32 MB.
// R12 POST-MORTEM: identical kernel WITHOUT launch_bounds spilled --
// hipcc's default (1024-thr schedulability) capped the allocator at 64
// VGPR (observed VGPR_Count=64) while acc[8][4] f32x4 alone needs 128;
// scratch traffic 119MB W + 59MB R per dispatch, 84.9us, MfmaUtil 1.8%.
// FIX (single change): __launch_bounds__(512, 1) -- min-waves=1/EU lets
// the allocator use up to 512 VGPRs (~200 needed -> no spill), and 8
// waves/block still gives 2 waves/SIMD.
// 512 threads = 8 waves in a 2x4 grid; each wave owns 128x64.
// LDS: 2 x 256x136 bf16 = 139KB (<160) + 6KB reduce buffers; padded-136
// rows keep the free 2-way bank pattern. Atomic output path (R10:
// partials +18us). No fences (R6), no swizzle (R4).
// ---------------------------------------------------------------------------
__global__ __launch_bounds__(512, 1) void gemm_exp_kernel(
    const bf16_t* __restrict__ zi, const bf16_t* __restrict__ zj,
    float* __restrict__ rowDenom, float* __restrict__ colDenom)
{
    __shared__ __align__(16) bf16_t zi_s[TILE][136];
    __shared__ __align__(16) bf16_t zj_s[TILE][136];
    __shared__ float rowRed[4][TILE];
    __shared__ float colRed[2][TILE];

    const int tid = threadIdx.x;
    const int ti = blockIdx.x, tj = blockIdx.y;

    // Stage 256x128 bf16 of each matrix: 4096 16B-chunks / matrix, 8 iters.
#pragma unroll
    for (int it = 0; it < 8; ++it) {
        int c = it * 512 + tid;
        int row = c >> 4;          // 16 chunks per row
        int col = (c & 15) << 3;   // 8 bf16 per chunk
        *(uint4*)&zi_s[row][col] =
            *(const uint4*)(zi + ((size_t)(ti * TILE + row)) * DIM + col);
        *(uint4*)&zj_s[row][col] =
            *(const uint4*)(zj + ((size_t)(tj * TILE + row)) * DIM + col);
    }
    __syncthreads();

    const int wave = tid >> 6;
    const int lane = tid & 63;
    const int l15  = lane & 15;
    const int quad = lane >> 4;
    const int wr   = wave >> 2;   // 0..1 : row half    (128 rows)
    const int wc   = wave & 3;    // 0..3 : col quarter (64 cols)

    const f32x4 vzero = {0.f, 0.f, 0.f, 0.f};
    f32x4 acc[8][4];
#pragma unroll
    for (int mr = 0; mr < 8; ++mr)
#pragma unroll
        for (int nc = 0; nc < 4; ++nc) acc[mr][nc] = vzero;

#pragma unroll
    for (int ks = 0; ks < 4; ++ks) {
        int k0 = ks * 32 + quad * 8;
        bf16x8 afrag[8], bfrag[4];
#pragma unroll
        for (int mr = 0; mr < 8; ++mr)
            afrag[mr] = *(const bf16x8*)&zi_s[wr * 128 + mr * 16 + l15][k0];
#pragma unroll
        for (int nc = 0; nc < 4; ++nc)
            bfrag[nc] = *(const bf16x8*)&zj_s[wc * 64 + nc * 16 + l15][k0];
#pragma unroll
        for (int mr = 0; mr < 8; ++mr)
#pragma unroll
            for (int nc = 0; nc < 4; ++nc)
                acc[mr][nc] = __builtin_amdgcn_mfma_f32_16x16x32_bf16(
                    afrag[mr], bfrag[nc], acc[mr][nc], 0, 0, 0);
    }

    // Epilogue: exp and partial sums.
    // C/D layout: col = l15, row = quad*4 + r (within each 16x16 frag).
    float rowPart[8][4];
    float colPart[4] = {0.f, 0.f, 0.f, 0.f};
#pragma unroll
    for (int mr = 0; mr < 8; ++mr)
#pragma unroll
        for (int r = 0; r < 4; ++r) rowPart[mr][r] = 0.f;

#pragma unroll
    for (int mr = 0; mr < 8; ++mr)
#pragma unroll
        for (int nc = 0; nc < 4; ++nc)
#pragma unroll
            for (int r = 0; r < 4; ++r) {
                float e = exp2f(acc[mr][nc][r] * EXP_SCALE);
                rowPart[mr][r] += e;   // row = wr*128 + mr*16 + quad*4 + r
                colPart[nc]    += e;   // col = wc*64  + nc*16 + l15
            }

    // Row sums: 16-lane shfl completes this wave's 64 cols; cross-wave
    // (4 wc-waves) via LDS.
#pragma unroll
    for (int mr = 0; mr < 8; ++mr)
#pragma unroll
        for (int r = 0; r < 4; ++r) {
            float v = rowPart[mr][r];
            v += __shfl_xor(v, 1);
            v += __shfl_xor(v, 2);
            v += __shfl_xor(v, 4);
            v += __shfl_xor(v, 8);
            if (l15 == 0)
                rowRed[wc][wr * 128 + mr * 16 + quad * 4 + r] = v;
        }

    // Col sums: quad shfl-reduce completes this wave's 128 rows;
    // cross-wave (2 wr-waves) via LDS.
#pragma unroll
    for (int nc = 0; nc < 4; ++nc) {
        float v = colPart[nc];
        v += __shfl_xor(v, 16);
        v += __shfl_xor(v, 32);
        if (quad == 0) colRed[wr][wc * 64 + nc * 16 + l15] = v;
    }
    __syncthreads();

    if (tid < TILE) {
        float rs = rowRed[0][tid] + rowRed[1][tid] + rowRed[2][tid] + rowRed[3][tid];
        atomicAdd(&rowDenom[ti * TILE + tid], rs);
        float cs = colRed[0][tid] + colRed[1][tid];
        atomicAdd(&colDenom[tj * TILE + tid], cs);
    }
}

// ---------------------------------------------------------------------------
// Kernel C: 1 block x 1024 threads; 3 independent float4 loads per thread,
// 8 logf, wave shfl-reduce, 16-way LDS reduce (R8 version).
// ---------------------------------------------------------------------------
__global__ __launch_bounds__(1024) void finalize_kernel(
    const float* __restrict__ denoms, const float* __restrict__ pos,
    float* __restrict__ out)
{
    const float4* rowD4 = (const float4*)denoms;            // 1024 float4
    const float4* colD4 = (const float4*)(denoms + BATCH);  // 1024 float4
    const float4* pos4  = (const float4*)pos;               // 1024 float4

    const int tid  = threadIdx.x;
    const int lane = tid & 63;
    const int wv   = tid >> 6;

    float4 rd = rowD4[tid];
    float4 cd = colD4[tid];
    float4 p  = pos4[tid];

    float acc = logf(rd.x) + logf(rd.y) + logf(rd.z) + logf(rd.w)
              + logf(cd.x) + logf(cd.y) + logf(cd.z) + logf(cd.w)
              - 8.0f * (p.x + p.y + p.z + p.w);

#pragma unroll
    for (int m = 1; m < 64; m <<= 1) acc += __shfl_xor(acc, m);

    __shared__ float red[16];
    if (lane == 0) red[wv] = acc;
    __syncthreads();
    if (wv == 0) {
        float v = (lane < 16) ? red[lane] : 0.0f;
#pragma unroll
        for (int m = 1; m < 64; m <<= 1) v += __shfl_xor(v, m);
        if (lane == 0) out[0] = v * (1.0f / (2.0f * BATCH));
    }
}

extern "C" void kernel_launch(void* const* d_in, const int* in_sizes, int n_in,
                              void* d_out, int out_size, void* d_ws, size_t ws_size,
                              hipStream_t stream) {
    const float* emb_i = (const float*)d_in[0];
    const float* emb_j = (const float*)d_in[1];
    float* out = (float*)d_out;

    char* ws = (char*)d_ws;
    bf16_t* zi     = (bf16_t*)(ws);                 // 1 MB
    bf16_t* zj     = (bf16_t*)(ws + (1u << 20));    // 1 MB
    float*  denoms = (float*)(ws + (2u << 20));     // 32 KB (row ++ col)
    float*  pos    = denoms + 2 * BATCH;            // 16 KB

    normalize_kernel<<<BATCH / 4, 256, 0, stream>>>(emb_i, emb_j, zi, zj, pos, denoms);
    gemm_exp_kernel<<<dim3(NT, NT), 512, 0, stream>>>(zi, zj, denoms, denoms + BATCH);
    finalize_kernel<<<1, 1024, 0, stream>>>(denoms, pos, out);
}